// Round 4
// baseline (85.904 us; speedup 1.0000x reference)
//
#include <hip/hip_runtime.h>
#include <math.h>

// Problem constants
#define B_   4
#define N_   1024
#define K_   520
#define C2   128
#define NK   (N_*K_)
#define NROWS (B_*N_)                 // 4096
#define CNT1  ((float)(B_*N_*K_))     // 2129920
#define CNT2  ((float)(B_*N_))        // 4096
#define EPS_  1e-5f

// Workspace layout (float offsets). Total 1,868,160 floats ~= 7.5 MB.
#define OFF_SC1     0                          // sc1[64], sh1[64]
#define OFF_SC2     128                        // sc2[128], sh2[128]
#define OFF_PART1   384                        // 1024 x 32 moment partials
#define OFF_PART2   (OFF_PART1 + 1024*32)      // 512 x 256
#define OFF_M1      (OFF_PART2 + 512*256)      // 4096*64   max_k h1, [row][c]
#define OFF_H2      (OFF_M1 + 4096*64)         // 4096*128  [col][o]
#define OFF_W3T     (OFF_H2 + 4096*128)        // 128*1024  w3^T [i][o]
#define OFF_PSUM    (OFF_W3T + 128*1024)       // 256*1024  per-tile sums of h3
#define OFF_PSQ     (OFF_PSUM + 256*1024)      // 256*1024
#define OFF_PMAX    (OFF_PSQ + 256*1024)       // 256*1024

// ---------------- K1: conv1 max over K + 27 global moment partials ----------------
// REGISTER-RESIDENT redesign: lane = k (not channel). Each wave owns ONE row;
// lane l holds k = {l, 64+l, ..., 448+l} (+512+l for l<8) of i0,i1,i2 in regs
// (27 coalesced global loads, no LDS staging). Channel loop c=0..63 reads one
// broadcast float4 of packed weights + computes 9x(3FMA+max), then a 6-step
// shfl_xor max-butterfly; lane==c keeps the result. This removes the old
// broadcast-b128 LDS bottleneck (~408 reads/row @ 16B/slot = LDS-issue-bound).
// Moment slots per block (part1[bid][32]):
//  0-5: Mg=sum[i0i0,i0i1,i0i2,i1i1,i1i2,i2i2]; 6-8: Sg=sum[i0,i1,i2]
//  9-17: P[i][j]=sum_r S_i(r)x_j(r); 18-23: Q=sum_r xx^T; 24-26: X=sum_r x
__global__ __launch_bounds__(256) void k1_feat(const float* __restrict__ x,
                                               const float* __restrict__ ips,
                                               const float* __restrict__ w1,
                                               const float* __restrict__ b1,
                                               float* __restrict__ ws) {
    __shared__ __align__(16) float wpk[64][4];     // wc0,wc1,wc2,(pad)
    __shared__ float base1s[4][64];
    __shared__ __align__(16) float mom[4][28];
    float* m1    = ws + OFF_M1;
    float* part1 = ws + OFF_PART1;
    const int t = threadIdx.x;
    const int wv = t >> 6, lane = t & 63;
    const int row = blockIdx.x * 4 + wv;           // 1024 blocks x 4 rows
    const int b = row >> 10, n = row & 1023;

    if (t < 64) {                                  // pack conv weights once
        wpk[t][0] = w1[t*6+0];
        wpk[t][1] = w1[t*6+1];
        wpk[t][2] = w1[t*6+2];
        wpk[t][3] = 0.f;
    }
    const float x0 = x[(b*3+0)*N_ + n];            // wave-uniform scalar loads
    const float x1 = x[(b*3+1)*N_ + n];
    const float x2 = x[(b*3+2)*N_ + n];
    {   // base1_c = wd.x + bb for this row, lane = c
        int c = lane;
        float wd0 = w1[c*6+3] - w1[c*6+0];
        float wd1 = w1[c*6+4] - w1[c*6+1];
        float wd2 = w1[c*6+5] - w1[c*6+2];
        base1s[wv][c] = fmaf(wd0, x0, fmaf(wd1, x1, fmaf(wd2, x2, b1[c])));
    }
    // ---- load this lane's k-samples to registers (coalesced, 256B/instr) ----
    const size_t gbase = ((size_t)(b*3)*N_ + n)*(size_t)K_;
    float a0[9], a1[9], a2[9];
    #pragma unroll
    for (int j = 0; j < 8; ++j) {
        a0[j] = ips[gbase          + j*64 + lane];
        a1[j] = ips[gbase +   NK   + j*64 + lane];
        a2[j] = ips[gbase + 2*NK   + j*64 + lane];
    }
    const bool extra = (lane < 8);                 // k = 512..519
    {
        int keo = extra ? (512 + lane) : 0;        // clamp to stay in-bounds
        float v0 = ips[gbase + keo];
        float v1 = ips[gbase + NK + keo];
        float v2 = ips[gbase + 2*NK + keo];
        a0[8] = extra ? v0 : 0.f;                  // zeros are moment-neutral
        a1[8] = extra ? v1 : 0.f;
        a2[8] = extra ? v2 : 0.f;
    }
    __syncthreads();
    // ---- channel loop: per-channel max over K ----
    float mval = 0.f;
    #pragma unroll 4
    for (int c = 0; c < 64; ++c) {
        float4 wp = *(const float4*)wpk[c];        // broadcast b128 (1/ch)
        float bs  = base1s[wv][c];                 // broadcast b32
        float vm = -INFINITY;
        #pragma unroll
        for (int j = 0; j < 8; ++j) {
            float h = fmaf(wp.x, a0[j], fmaf(wp.y, a1[j], fmaf(wp.z, a2[j], bs)));
            vm = fmaxf(vm, h);
        }
        {   float h = fmaf(wp.x, a0[8], fmaf(wp.y, a1[8], fmaf(wp.z, a2[8], bs)));
            vm = fmaxf(vm, extra ? h : -INFINITY); // exclude pad lanes from max
        }
        #pragma unroll
        for (int off = 32; off > 0; off >>= 1) vm = fmaxf(vm, __shfl_xor(vm, off));
        if (lane == c) mval = vm;                  // cndmask select
    }
    m1[(size_t)row * 64 + lane] = mval;            // [row][c], coalesced
    // ---- moments from the same registers ----
    float m00=0.f,m01=0.f,m02=0.f,m11=0.f,m12=0.f,m22=0.f,s0=0.f,s1=0.f,s2=0.f;
    #pragma unroll
    for (int j = 0; j < 9; ++j) {
        float i0 = a0[j], i1v = a1[j], i2v = a2[j];
        m00 = fmaf(i0,  i0,  m00); m01 = fmaf(i0,  i1v, m01); m02 = fmaf(i0,  i2v, m02);
        m11 = fmaf(i1v, i1v, m11); m12 = fmaf(i1v, i2v, m12); m22 = fmaf(i2v, i2v, m22);
        s0 += i0; s1 += i1v; s2 += i2v;
    }
    #pragma unroll
    for (int off = 32; off > 0; off >>= 1) {
        m00 += __shfl_xor(m00, off); m01 += __shfl_xor(m01, off); m02 += __shfl_xor(m02, off);
        m11 += __shfl_xor(m11, off); m12 += __shfl_xor(m12, off); m22 += __shfl_xor(m22, off);
        s0  += __shfl_xor(s0,  off); s1  += __shfl_xor(s1,  off); s2  += __shfl_xor(s2,  off);
    }
    if (lane == 0) {
        float* mo = mom[wv];
        mo[0]=m00; mo[1]=m01; mo[2]=m02; mo[3]=m11; mo[4]=m12; mo[5]=m22;
        mo[6]=s0;  mo[7]=s1;  mo[8]=s2;
        mo[9] =s0*x0; mo[10]=s0*x1; mo[11]=s0*x2;
        mo[12]=s1*x0; mo[13]=s1*x1; mo[14]=s1*x2;
        mo[15]=s2*x0; mo[16]=s2*x1; mo[17]=s2*x2;
        mo[18]=x0*x0; mo[19]=x0*x1; mo[20]=x0*x2; mo[21]=x1*x1; mo[22]=x1*x2; mo[23]=x2*x2;
        mo[24]=x0; mo[25]=x1; mo[26]=x2;
    }
    __syncthreads();
    if (t < 27) part1[blockIdx.x*32 + t] = mom[0][t] + mom[1][t] + mom[2][t] + mom[3][t];
}

// ---------------- K2: reduce moments -> BN1 scale/shift ----------------
__global__ __launch_bounds__(512) void k2_red1(const float* __restrict__ w1,
                                               const float* __restrict__ b1,
                                               const float* __restrict__ g1,
                                               const float* __restrict__ be1,
                                               float* __restrict__ ws) {
    __shared__ float lds[512];
    __shared__ float mo[32];
    const int t = threadIdx.x;
    const float* part1 = ws + OFF_PART1;
    const int s = t & 31, g = t >> 5;               // 16 stripes
    float acc = 0.f;
    if (s < 27) {
        for (int j = 0; j < 64; ++j) acc += part1[(g*64 + j)*32 + s];
    }
    lds[t] = acc;
    __syncthreads();
    if (t < 32) {
        float m = 0.f;
        for (int gg = 0; gg < 16; ++gg) m += lds[gg*32 + t];
        mo[t] = m;
    }
    __syncthreads();
    if (t < 64) {
        const int c = t;
        float w0 = w1[c*6+0], w1v = w1[c*6+1], w2v = w1[c*6+2];
        float wd0 = w1[c*6+3]-w0, wd1 = w1[c*6+4]-w1v, wd2 = w1[c*6+5]-w2v;
        float bb = b1[c];
        float S0 = mo[6], S1 = mo[7], S2 = mo[8];
        float X0 = mo[24], X1 = mo[25], X2 = mo[26];
        float wcS = w0*S0 + w1v*S1 + w2v*S2;
        float wdX = wd0*X0 + wd1*X1 + wd2*X2;
        float ssum = wcS + 520.f*(wdX + 4096.f*bb);
        float t1 = w0*w0*mo[0] + w1v*w1v*mo[3] + w2v*w2v*mo[5]
                 + 2.f*(w0*w1v*mo[1] + w0*w2v*mo[2] + w1v*w2v*mo[4]);
        float Pt = w0 *(mo[9]*wd0  + mo[10]*wd1 + mo[11]*wd2)
                 + w1v*(mo[12]*wd0 + mo[13]*wd1 + mo[14]*wd2)
                 + w2v*(mo[15]*wd0 + mo[16]*wd1 + mo[17]*wd2);
        float t2 = 2.f*(Pt + bb*wcS);
        float Qt = wd0*wd0*mo[18] + wd1*wd1*mo[21] + wd2*wd2*mo[23]
                 + 2.f*(wd0*wd1*mo[19] + wd0*wd2*mo[20] + wd1*wd2*mo[22]);
        float t3 = 520.f*(Qt + 2.f*bb*wdX + 4096.f*bb*bb);
        float ssq = t1 + t2 + t3;
        float mean = ssum * (1.f / CNT1);
        float var  = ssq * (1.f / CNT1) - mean*mean;
        float sc   = g1[c] * rsqrtf(var + EPS_);
        ws[OFF_SC1 + c]      = sc;
        ws[OFF_SC1 + 64 + c] = fmaf(-mean, sc, be1[c]);
    }
}

// ---------------- K3: w3 transpose + r1=relu(BN1(m1)); h2 = w2@r1+b2; BN2 partials
// 512 blocks x 8 columns. 256 threads = 2 col-groups x 128 out-ch.
__global__ __launch_bounds__(256) void k3_l2(const float* __restrict__ w2,
                                             const float* __restrict__ b2,
                                             const float* __restrict__ w3,
                                             float* __restrict__ ws) {
    __shared__ float w2l[C2 * 65];
    __shared__ float sc1[64], sh1[64];
    __shared__ float r1c[128];
    __shared__ float lred[256];
    const int t = threadIdx.x;
    const float* m1 = ws + OFF_M1;
    float* h2    = ws + OFF_H2;
    float* part2 = ws + OFF_PART2;
    float* w3t   = ws + OFF_W3T;
    {   // fold w3 transpose: block covers 256 w3t elements
        int idx = blockIdx.x * 256 + t;
        int i = idx >> 10, o = idx & 1023;
        w3t[idx] = w3[o * 128 + i];
    }
    if (t < 64) { sc1[t] = ws[OFF_SC1 + t]; sh1[t] = ws[OFF_SC1 + 64 + t]; }
    for (int idx = t; idx < C2 * 64; idx += 256) {
        int o = idx >> 6, i = idx & 63;
        w2l[o * 65 + i] = w2[idx];
    }
    const int o = t & 127, cg = t >> 7;
    const float bo = b2[o];
    float s2 = 0.f, q2 = 0.f;
    const int colbase = blockIdx.x * 8;
    __syncthreads();
    for (int it = 0; it < 4; ++it) {
        __syncthreads();
        if (t < 128) {
            int ci = t & 63, g = t >> 6;
            float v = m1[(size_t)(colbase + it * 2 + g) * 64 + ci];
            r1c[t] = fmaxf(0.f, fmaf(v, sc1[ci], sh1[ci]));
        }
        __syncthreads();
        float acc = 0.f;
        const float* wr = w2l + o * 65;
        const float* rr = r1c + cg * 64;
        #pragma unroll 8
        for (int i = 0; i < 64; ++i) acc = fmaf(wr[i], rr[i], acc);
        float h = acc + bo;
        h2[(size_t)(colbase + it * 2 + cg) * 128 + o] = h;
        s2 += h;
        q2 = fmaf(h, h, q2);
    }
    __syncthreads();
    lred[t] = s2;
    __syncthreads();
    if (t < 128) part2[blockIdx.x * 256 + t] = lred[t] + lred[128 + t];
    __syncthreads();
    lred[t] = q2;
    __syncthreads();
    if (t < 128) part2[blockIdx.x * 256 + 128 + t] = lred[t] + lred[128 + t];
}

// ---------------- K4: reduce part2 (512x256) -> BN2 scale/shift ----------------
__global__ __launch_bounds__(256) void k4_red2(const float* __restrict__ g2,
                                               const float* __restrict__ be2,
                                               float* __restrict__ ws) {
    __shared__ float lsum[256], lsq[256];
    const int t = threadIdx.x;
    const int c = blockIdx.x;                       // 0..127
    const float* part2 = ws + OFF_PART2;
    lsum[t] = part2[t*256 + c]       + part2[(t+256)*256 + c];
    lsq[t]  = part2[t*256 + 128 + c] + part2[(t+256)*256 + 128 + c];
    __syncthreads();
    for (int st = 128; st > 0; st >>= 1) {
        if (t < st) { lsum[t] += lsum[t + st]; lsq[t] += lsq[t + st]; }
        __syncthreads();
    }
    if (t == 0) {
        float mean = lsum[0] * (1.f / CNT2);
        float var  = lsq[0] * (1.f / CNT2) - mean*mean;
        float sc   = g2[c] * rsqrtf(var + EPS_);
        ws[OFF_SC2 + c]       = sc;
        ws[OFF_SC2 + 128 + c] = fmaf(-mean, sc, be2[c]);
    }
}

// ---------------- K5: r2 = relu(BN2(h2)); h3 = w3@r2+b3; tile partials ----------
// 256 blocks x 512 threads; tile = 16 consecutive n of one b, all 1024 channels.
__global__ __launch_bounds__(512) void k5_l3(const float* __restrict__ b3,
                                             float* __restrict__ ws) {
    __shared__ __align__(16) float r2t[128 * 16];
    __shared__ float sc2[128], sh2[128];
    const int t = threadIdx.x;
    const float* h2  = ws + OFF_H2;
    const float* w3t = ws + OFF_W3T;
    float* psum = ws + OFF_PSUM;
    float* psq  = ws + OFF_PSQ;
    float* pmax = ws + OFF_PMAX;
    const int tile = blockIdx.x;                    // 0..255
    const int b = tile >> 6, n0 = (tile & 63) * 16;
    if (t < 128) { sc2[t] = ws[OFF_SC2 + t]; sh2[t] = ws[OFF_SC2 + 128 + t]; }
    __syncthreads();
    #pragma unroll
    for (int m = 0; m < 4; ++m) {                   // stage r2 tile [i][col]
        int idx = t + 512 * m;
        int col = idx >> 7, i = idx & 127;
        float v = h2[(size_t)(b * N_ + n0 + col) * 128 + i];
        r2t[i * 16 + col] = fmaxf(0.f, fmaf(v, sc2[i], sh2[i]));
    }
    __syncthreads();
    float acc[2][16];
    #pragma unroll
    for (int a = 0; a < 2; ++a)
        #pragma unroll
        for (int cl = 0; cl < 16; ++cl) acc[a][cl] = 0.f;
    const float2* w3t2 = (const float2*)w3t;
    for (int i = 0; i < 128; ++i) {
        float2 w = w3t2[i * 512 + t];               // coalesced, L2-resident
        float wa0 = w.x, wa1 = w.y;
        const float4* rp = (const float4*)(r2t + i * 16);
        #pragma unroll
        for (int q = 0; q < 4; ++q) {
            float4 r4 = rp[q];                      // broadcast LDS read
            float rc[4] = {r4.x, r4.y, r4.z, r4.w};
            #pragma unroll
            for (int jj = 0; jj < 4; ++jj) {
                acc[0][q*4+jj] = fmaf(wa0, rc[jj], acc[0][q*4+jj]);
                acc[1][q*4+jj] = fmaf(wa1, rc[jj], acc[1][q*4+jj]);
            }
        }
    }
    float2 b3v = ((const float2*)b3)[t];
    float bav[2] = {b3v.x, b3v.y};
    float2 vs, vq, vm;
    float* pvs = (float*)&vs; float* pvq = (float*)&vq; float* pvm = (float*)&vm;
    #pragma unroll
    for (int a = 0; a < 2; ++a) {
        float s = 0.f, q = 0.f, mx = -INFINITY;
        #pragma unroll
        for (int cl = 0; cl < 16; ++cl) {
            float v = acc[a][cl] + bav[a];
            s += v;
            q = fmaf(v, v, q);
            mx = fmaxf(mx, v);
        }
        pvs[a] = s; pvq[a] = q; pvm[a] = mx;
    }
    ((float2*)psum)[tile * 512 + t] = vs;           // [tile][c], coalesced
    ((float2*)psq )[tile * 512 + t] = vq;
    ((float2*)pmax)[tile * 512 + t] = vm;
}

// ---------------- K6: BN3 stats from tiles; max over n; output ------------------
__global__ __launch_bounds__(256) void k6_out(const float* __restrict__ g3,
                                              const float* __restrict__ be3,
                                              float* __restrict__ out,
                                              const float* __restrict__ ws) {
    __shared__ float lsum[256], lsq[256], lmax[256];
    const int t = threadIdx.x;
    const int c = blockIdx.x;
    const float* psum = ws + OFF_PSUM;
    const float* psq  = ws + OFF_PSQ;
    const float* pmax = ws + OFF_PMAX;
    lsum[t] = psum[(size_t)t * 1024 + c];
    lsq[t]  = psq [(size_t)t * 1024 + c];
    lmax[t] = pmax[(size_t)t * 1024 + c];
    __syncthreads();
    for (int s = 128; s > 0; s >>= 1) {
        if (t < s) { lsum[t] += lsum[t + s]; lsq[t] += lsq[t + s]; }
        __syncthreads();
    }
    float mean = lsum[0] * (1.f / CNT2);
    float var  = lsq[0] * (1.f / CNT2) - mean * mean;
    float rs   = rsqrtf(var + EPS_);
    float sc   = g3[c] * rs;
    float sh   = fmaf(-mean, sc, be3[c]);
    const int wv = t >> 6, l = t & 63;
    float v = lmax[wv * 64 + l];                    // tile = wv*64+l is batch wv
    #pragma unroll
    for (int off = 32; off > 0; off >>= 1) v = fmaxf(v, __shfl_xor(v, off));
    if (l == 0) out[wv * 1024 + c] = fmaf(v, sc, sh);
}

extern "C" void kernel_launch(void* const* d_in, const int* in_sizes, int n_in,
                              void* d_out, int out_size, void* d_ws, size_t ws_size,
                              hipStream_t stream) {
    const float* x   = (const float*)d_in[0];
    const float* ips = (const float*)d_in[1];
    const float* w1  = (const float*)d_in[2];
    const float* b1  = (const float*)d_in[3];
    const float* g1  = (const float*)d_in[4];
    const float* be1 = (const float*)d_in[5];
    const float* w2  = (const float*)d_in[6];
    const float* b2  = (const float*)d_in[7];
    const float* g2  = (const float*)d_in[8];
    const float* be2 = (const float*)d_in[9];
    const float* w3  = (const float*)d_in[10];
    const float* b3  = (const float*)d_in[11];
    const float* g3  = (const float*)d_in[12];
    const float* be3 = (const float*)d_in[13];
    float* out = (float*)d_out;
    float* ws  = (float*)d_ws;

    hipLaunchKernelGGL(k1_feat, dim3(1024), dim3(256), 0, stream, x, ips, w1, b1, ws);
    hipLaunchKernelGGL(k2_red1, dim3(1),    dim3(512), 0, stream, w1, b1, g1, be1, ws);
    hipLaunchKernelGGL(k3_l2,   dim3(512),  dim3(256), 0, stream, w2, b2, w3, ws);
    hipLaunchKernelGGL(k4_red2, dim3(128),  dim3(256), 0, stream, g2, be2, ws);
    hipLaunchKernelGGL(k5_l3,   dim3(256),  dim3(512), 0, stream, b3, ws);
    hipLaunchKernelGGL(k6_out,  dim3(1024), dim3(256), 0, stream, g3, be3, out, ws);
}

// Round 7
// 74.410 us; speedup vs baseline: 1.1545x; 1.1545x over previous
//
#include <hip/hip_runtime.h>
#include <math.h>

// Problem constants
#define B_   4
#define N_   1024
#define K_   520
#define C2   128
#define NK   (N_*K_)
#define NROWS (B_*N_)                 // 4096
#define CNT1  ((float)(B_*N_*K_))     // 2129920
#define CNT2  ((float)(B_*N_))       // 4096
#define EPS_  1e-5f

// Workspace layout (float offsets) — identical to Round 4 (passing).
#define OFF_SC1     0                          // sc1[64], sh1[64]
#define OFF_SC2     128                        // sc2[128], sh2[128]
#define OFF_PART1   384                        // 1024 x 32 moment partials
#define OFF_PART2   (OFF_PART1 + 1024*32)      // 512 x 256
#define OFF_M1      (OFF_PART2 + 512*256)      // 4096*64   max_k h1, [row][c]
#define OFF_H2      (OFF_M1 + 4096*64)         // 4096*128  [col][o]
#define OFF_W3T     (OFF_H2 + 4096*128)        // 128*1024  w3^T [i][o]
#define OFF_PSUM    (OFF_W3T + 128*1024)       // 256*1024  per-tile sums of h3
#define OFF_PSQ     (OFF_PSUM + 256*1024)      // 256*1024
#define OFF_PMAX    (OFF_PSQ + 256*1024)       // 256*1024

// ---------------- K1: conv1 (6->64) + max over K + 27 moment partials -----------
// 1024 blocks x 256 thr; wave wv owns row = bid*4+wv. Lane = k: each lane holds
// k = {l, 64+l, ..., 448+l} (+512+l if l<8) of (i0,i1,i2) in registers (27
// coalesced loads, no staging). Channel maxima in two 32-channel batches via an
// LDS transpose: write lt[wv][ci][lane] (consecutive lanes -> conflict-free),
// read lt[wv][lane&31][half*32+j] (2 lanes/bank = free), finish with one
// shfl_xor(32). Moments reduce from the same registers (proven in R4).
__global__ __launch_bounds__(256) void k1_feat(const float* __restrict__ x,
                                               const float* __restrict__ ips,
                                               const float* __restrict__ w1,
                                               const float* __restrict__ b1,
                                               float* __restrict__ ws) {
    __shared__ __align__(16) float wts[64][4];     // wc0,wc1,wc2,b1
    __shared__ float wds[64][4];                   // wd0,wd1,wd2,pad
    __shared__ float base1s[4][64];
    __shared__ float lt[4][32][65];                // 33280 B; total LDS ~37 KB
    __shared__ float mom[4][28];
    float* m1    = ws + OFF_M1;
    float* part1 = ws + OFF_PART1;
    const int t = threadIdx.x;
    const int wv = t >> 6, lane = t & 63;
    const int row = blockIdx.x * 4 + wv;
    const int b = row >> 10, n = row & 1023;

    if (t < 64) {
        float w0 = w1[t*6+0], w1v = w1[t*6+1], w2v = w1[t*6+2];
        wts[t][0] = w0;  wts[t][1] = w1v;  wts[t][2] = w2v;  wts[t][3] = b1[t];
        wds[t][0] = w1[t*6+3]-w0;  wds[t][1] = w1[t*6+4]-w1v;
        wds[t][2] = w1[t*6+5]-w2v; wds[t][3] = 0.f;
    }
    __syncthreads();
    const float x0 = x[(b*3+0)*N_ + n];            // wave-uniform
    const float x1 = x[(b*3+1)*N_ + n];
    const float x2 = x[(b*3+2)*N_ + n];
    {   // base1 per channel (lane = c)
        const float* wd = wds[lane];
        base1s[wv][lane] = fmaf(wd[0], x0, fmaf(wd[1], x1, fmaf(wd[2], x2, wts[lane][3])));
    }
    // ---- register loads: lane l holds 9 k-samples of each input channel ----
    const size_t gb = ((size_t)(b*3)*N_ + n) * (size_t)K_;
    float a0[9], a1[9], a2[9];
    #pragma unroll
    for (int j = 0; j < 8; ++j) {
        a0[j] = ips[gb        + j*64 + lane];
        a1[j] = ips[gb +   NK + j*64 + lane];
        a2[j] = ips[gb + 2*NK + j*64 + lane];
    }
    const bool extra = (lane < 8);
    {
        int keo = extra ? (512 + lane) : lane;
        float v0 = ips[gb + keo], v1 = ips[gb + NK + keo], v2 = ips[gb + 2*NK + keo];
        a0[8] = extra ? v0 : 0.f;  a1[8] = extra ? v1 : 0.f;  a2[8] = extra ? v2 : 0.f;
    }
    // ---- per-channel max over K, two batches of 32 channels ----
    float m_out0 = 0.f, m_out1 = 0.f;
    #pragma unroll
    for (int cb = 0; cb < 2; ++cb) {
        #pragma unroll 8
        for (int ci = 0; ci < 32; ++ci) {
            const int c = cb*32 + ci;
            const float4 wt = *(const float4*)wts[c];      // broadcast b128
            const float bs = base1s[wv][c];                // broadcast b32
            float vm = -INFINITY;
            #pragma unroll
            for (int j = 0; j < 8; ++j) {
                float h = fmaf(wt.x, a0[j], fmaf(wt.y, a1[j], fmaf(wt.z, a2[j], bs)));
                vm = fmaxf(vm, h);
            }
            float h8  = fmaf(wt.x, a0[8], fmaf(wt.y, a1[8], fmaf(wt.z, a2[8], bs)));
            float vm2 = fmaxf(vm, h8);
            vm = extra ? vm2 : vm;                         // pad lanes exclude j=8
            lt[wv][ci][lane] = vm;                         // conflict-free write
        }
        // transpose reduce: lane -> channel cb*32+(lane&31), halves split j
        const int ci = lane & 31, half = lane >> 5;
        float p = -INFINITY;
        #pragma unroll
        for (int j = 0; j < 32; ++j) p = fmaxf(p, lt[wv][ci][half*32 + j]);
        p = fmaxf(p, __shfl_xor(p, 32));
        if (cb == 0) m_out0 = p; else m_out1 = p;
    }
    if (lane < 32) {                                       // two coalesced 128B stores
        m1[(size_t)row*64 + lane]      = m_out0;
        m1[(size_t)row*64 + 32 + lane] = m_out1;
    }
    // ---- moments from the same registers (algebra proven in R4) ----
    float mg0=0,mg1=0,mg2=0,mg3=0,mg4=0,mg5=0,s0=0,s1=0,s2=0;
    #pragma unroll
    for (int j = 0; j < 9; ++j) {
        float i0=a0[j], i1=a1[j], i2=a2[j];
        mg0=fmaf(i0,i0,mg0); mg1=fmaf(i0,i1,mg1); mg2=fmaf(i0,i2,mg2);
        mg3=fmaf(i1,i1,mg3); mg4=fmaf(i1,i2,mg4); mg5=fmaf(i2,i2,mg5);
        s0+=i0; s1+=i1; s2+=i2;
    }
    #pragma unroll
    for (int off=32; off>0; off>>=1) {
        mg0+=__shfl_xor(mg0,off); mg1+=__shfl_xor(mg1,off); mg2+=__shfl_xor(mg2,off);
        mg3+=__shfl_xor(mg3,off); mg4+=__shfl_xor(mg4,off); mg5+=__shfl_xor(mg5,off);
        s0 +=__shfl_xor(s0, off); s1 +=__shfl_xor(s1, off); s2 +=__shfl_xor(s2, off);
    }
    if (lane == 0) {
        float* mo = mom[wv];
        mo[0]=mg0; mo[1]=mg1; mo[2]=mg2; mo[3]=mg3; mo[4]=mg4; mo[5]=mg5;
        mo[6]=s0;  mo[7]=s1;  mo[8]=s2;
        mo[9] =s0*x0; mo[10]=s0*x1; mo[11]=s0*x2;
        mo[12]=s1*x0; mo[13]=s1*x1; mo[14]=s1*x2;
        mo[15]=s2*x0; mo[16]=s2*x1; mo[17]=s2*x2;
        mo[18]=x0*x0; mo[19]=x0*x1; mo[20]=x0*x2; mo[21]=x1*x1; mo[22]=x1*x2; mo[23]=x2*x2;
        mo[24]=x0; mo[25]=x1; mo[26]=x2;
    }
    __syncthreads();
    if (t < 27) part1[blockIdx.x*32 + t] = mom[0][t] + mom[1][t] + mom[2][t] + mom[3][t];
}

// ---------------- K2: reduce moments -> BN1 scale/shift (R4, passing) -----------
__global__ __launch_bounds__(512) void k2_red1(const float* __restrict__ w1,
                                               const float* __restrict__ b1,
                                               const float* __restrict__ g1,
                                               const float* __restrict__ be1,
                                               float* __restrict__ ws) {
    __shared__ float lds[512];
    __shared__ float mo[32];
    const int t = threadIdx.x;
    const float* part1 = ws + OFF_PART1;
    const int s = t & 31, g = t >> 5;               // 16 stripes
    float acc = 0.f;
    if (s < 27) {
        for (int j = 0; j < 64; ++j) acc += part1[(g*64 + j)*32 + s];
    }
    lds[t] = acc;
    __syncthreads();
    if (t < 32) {
        float m = 0.f;
        for (int gg = 0; gg < 16; ++gg) m += lds[gg*32 + t];
        mo[t] = m;
    }
    __syncthreads();
    if (t < 64) {
        const int c = t;
        float w0 = w1[c*6+0], w1v = w1[c*6+1], w2v = w1[c*6+2];
        float wd0 = w1[c*6+3]-w0, wd1 = w1[c*6+4]-w1v, wd2 = w1[c*6+5]-w2v;
        float bb = b1[c];
        float S0 = mo[6], S1 = mo[7], S2 = mo[8];
        float X0 = mo[24], X1 = mo[25], X2 = mo[26];
        float wcS = w0*S0 + w1v*S1 + w2v*S2;
        float wdX = wd0*X0 + wd1*X1 + wd2*X2;
        float ssum = wcS + 520.f*(wdX + 4096.f*bb);
        float t1 = w0*w0*mo[0] + w1v*w1v*mo[3] + w2v*w2v*mo[5]
                 + 2.f*(w0*w1v*mo[1] + w0*w2v*mo[2] + w1v*w2v*mo[4]);
        float Pt = w0 *(mo[9]*wd0  + mo[10]*wd1 + mo[11]*wd2)
                 + w1v*(mo[12]*wd0 + mo[13]*wd1 + mo[14]*wd2)
                 + w2v*(mo[15]*wd0 + mo[16]*wd1 + mo[17]*wd2);
        float t2 = 2.f*(Pt + bb*wcS);
        float Qt = wd0*wd0*mo[18] + wd1*wd1*mo[21] + wd2*wd2*mo[23]
                 + 2.f*(wd0*wd1*mo[19] + wd0*wd2*mo[20] + wd1*wd2*mo[22]);
        float t3 = 520.f*(Qt + 2.f*bb*wdX + 4096.f*bb*bb);
        float ssq = t1 + t2 + t3;
        float mean = ssum * (1.f / CNT1);
        float var  = ssq * (1.f / CNT1) - mean*mean;
        float sc   = g1[c] * rsqrtf(var + EPS_);
        ws[OFF_SC1 + c]      = sc;
        ws[OFF_SC1 + 64 + c] = fmaf(-mean, sc, be1[c]);
    }
}

// ---------------- K3: w3^T fill + FC2 (64->128) + BN2 partials (R4, passing) ----
__global__ __launch_bounds__(256) void k3_l2(const float* __restrict__ w2,
                                             const float* __restrict__ b2,
                                             const float* __restrict__ w3,
                                             float* __restrict__ ws) {
    __shared__ float w2l[C2 * 65];
    __shared__ float sc1[64], sh1[64];
    __shared__ float r1c[128];
    __shared__ float lred[256];
    const int t = threadIdx.x;
    const float* m1 = ws + OFF_M1;
    float* h2    = ws + OFF_H2;
    float* part2 = ws + OFF_PART2;
    float* w3t   = ws + OFF_W3T;
    {   // fold w3 transpose: block covers 256 w3t elements
        int idx = blockIdx.x * 256 + t;
        int i = idx >> 10, o = idx & 1023;
        w3t[idx] = w3[o * 128 + i];
    }
    if (t < 64) { sc1[t] = ws[OFF_SC1 + t]; sh1[t] = ws[OFF_SC1 + 64 + t]; }
    for (int idx = t; idx < C2 * 64; idx += 256) {
        int o = idx >> 6, i = idx & 63;
        w2l[o * 65 + i] = w2[idx];
    }
    const int o = t & 127, cg = t >> 7;
    const float bo = b2[o];
    float s2 = 0.f, q2 = 0.f;
    const int colbase = blockIdx.x * 8;
    __syncthreads();
    for (int it = 0; it < 4; ++it) {
        __syncthreads();
        if (t < 128) {
            int ci = t & 63, g = t >> 6;
            float v = m1[(size_t)(colbase + it * 2 + g) * 64 + ci];
            r1c[t] = fmaxf(0.f, fmaf(v, sc1[ci], sh1[ci]));
        }
        __syncthreads();
        float acc = 0.f;
        const float* wr = w2l + o * 65;
        const float* rr = r1c + cg * 64;
        #pragma unroll 8
        for (int i = 0; i < 64; ++i) acc = fmaf(wr[i], rr[i], acc);
        float h = acc + bo;
        h2[(size_t)(colbase + it * 2 + cg) * 128 + o] = h;
        s2 += h;
        q2 = fmaf(h, h, q2);
    }
    __syncthreads();
    lred[t] = s2;
    __syncthreads();
    if (t < 128) part2[blockIdx.x * 256 + t] = lred[t] + lred[128 + t];
    __syncthreads();
    lred[t] = q2;
    __syncthreads();
    if (t < 128) part2[blockIdx.x * 256 + 128 + t] = lred[t] + lred[128 + t];
}

// ---------------- K4: reduce part2 (512x256) -> BN2 scale/shift (R4, passing) ---
__global__ __launch_bounds__(256) void k4_red2(const float* __restrict__ g2,
                                               const float* __restrict__ be2,
                                               float* __restrict__ ws) {
    __shared__ float lsum[256], lsq[256];
    const int t = threadIdx.x;
    const int c = blockIdx.x;                       // 0..127
    const float* part2 = ws + OFF_PART2;
    lsum[t] = part2[t*256 + c]       + part2[(t+256)*256 + c];
    lsq[t]  = part2[t*256 + 128 + c] + part2[(t+256)*256 + 128 + c];
    __syncthreads();
    for (int st = 128; st > 0; st >>= 1) {
        if (t < st) { lsum[t] += lsum[t + st]; lsq[t] += lsq[t + st]; }
        __syncthreads();
    }
    if (t == 0) {
        float mean = lsum[0] * (1.f / CNT2);
        float var  = lsq[0] * (1.f / CNT2) - mean*mean;
        float sc   = g2[c] * rsqrtf(var + EPS_);
        ws[OFF_SC2 + c]       = sc;
        ws[OFF_SC2 + 128 + c] = fmaf(-mean, sc, be2[c]);
    }
}

// ---------------- K5: r2=relu(BN2(h2)); h3=w3@r2+b3; tile partials (R4) ---------
__global__ __launch_bounds__(512) void k5_l3(const float* __restrict__ b3,
                                             float* __restrict__ ws) {
    __shared__ __align__(16) float r2t[128 * 16];
    __shared__ float sc2[128], sh2[128];
    const int t = threadIdx.x;
    const float* h2  = ws + OFF_H2;
    const float* w3t = ws + OFF_W3T;
    float* psum = ws + OFF_PSUM;
    float* psq  = ws + OFF_PSQ;
    float* pmax = ws + OFF_PMAX;
    const int tile = blockIdx.x;                    // 0..255
    const int b = tile >> 6, n0 = (tile & 63) * 16;
    if (t < 128) { sc2[t] = ws[OFF_SC2 + t]; sh2[t] = ws[OFF_SC2 + 128 + t]; }
    __syncthreads();
    #pragma unroll
    for (int m = 0; m < 4; ++m) {                   // stage r2 tile [i][col]
        int idx = t + 512 * m;
        int col = idx >> 7, i = idx & 127;
        float v = h2[(size_t)(b * N_ + n0 + col) * 128 + i];
        r2t[i * 16 + col] = fmaxf(0.f, fmaf(v, sc2[i], sh2[i]));
    }
    __syncthreads();
    float acc[2][16];
    #pragma unroll
    for (int a = 0; a < 2; ++a)
        #pragma unroll
        for (int cl = 0; cl < 16; ++cl) acc[a][cl] = 0.f;
    const float2* w3t2 = (const float2*)w3t;
    for (int i = 0; i < 128; ++i) {
        float2 w = w3t2[i * 512 + t];               // coalesced, L2-resident
        float wa0 = w.x, wa1 = w.y;
        const float4* rp = (const float4*)(r2t + i * 16);
        #pragma unroll
        for (int q = 0; q < 4; ++q) {
            float4 r4 = rp[q];                      // broadcast LDS read
            float rc[4] = {r4.x, r4.y, r4.z, r4.w};
            #pragma unroll
            for (int jj = 0; jj < 4; ++jj) {
                acc[0][q*4+jj] = fmaf(wa0, rc[jj], acc[0][q*4+jj]);
                acc[1][q*4+jj] = fmaf(wa1, rc[jj], acc[1][q*4+jj]);
            }
        }
    }
    float2 b3v = ((const float2*)b3)[t];
    float bav[2] = {b3v.x, b3v.y};
    float2 vs, vq, vm;
    float* pvs = (float*)&vs; float* pvq = (float*)&vq; float* pvm = (float*)&vm;
    #pragma unroll
    for (int a = 0; a < 2; ++a) {
        float s = 0.f, q = 0.f, mx = -INFINITY;
        #pragma unroll
        for (int cl = 0; cl < 16; ++cl) {
            float v = acc[a][cl] + bav[a];
            s += v;
            q = fmaf(v, v, q);
            mx = fmaxf(mx, v);
        }
        pvs[a] = s; pvq[a] = q; pvm[a] = mx;
    }
    ((float2*)psum)[tile * 512 + t] = vs;           // [tile][c], coalesced
    ((float2*)psq )[tile * 512 + t] = vq;
    ((float2*)pmax)[tile * 512 + t] = vm;
}

// ---------------- K6: BN3 stats + max over n + output (R4, passing) -------------
__global__ __launch_bounds__(256) void k6_out(const float* __restrict__ g3,
                                              const float* __restrict__ be3,
                                              float* __restrict__ out,
                                              const float* __restrict__ ws) {
    __shared__ float lsum[256], lsq[256], lmax[256];
    const int t = threadIdx.x;
    const int c = blockIdx.x;
    const float* psum = ws + OFF_PSUM;
    const float* psq  = ws + OFF_PSQ;
    const float* pmax = ws + OFF_PMAX;
    lsum[t] = psum[(size_t)t * 1024 + c];
    lsq[t]  = psq [(size_t)t * 1024 + c];
    lmax[t] = pmax[(size_t)t * 1024 + c];
    __syncthreads();
    for (int s = 128; s > 0; s >>= 1) {
        if (t < s) { lsum[t] += lsum[t + s]; lsq[t] += lsq[t + s]; }
        __syncthreads();
    }
    float mean = lsum[0] * (1.f / CNT2);
    float var  = lsq[0] * (1.f / CNT2) - mean * mean;
    float rs   = rsqrtf(var + EPS_);
    float sc   = g3[c] * rs;
    float sh   = fmaf(-mean, sc, be3[c]);
    const int wv = t >> 6, l = t & 63;
    float v = lmax[wv * 64 + l];                    // tile = wv*64+l is batch wv
    #pragma unroll
    for (int off = 32; off > 0; off >>= 1) v = fmaxf(v, __shfl_xor(v, off));
    if (l == 0) out[wv * 1024 + c] = fmaf(v, sc, sh);
}

extern "C" void kernel_launch(void* const* d_in, const int* in_sizes, int n_in,
                              void* d_out, int out_size, void* d_ws, size_t ws_size,
                              hipStream_t stream) {
    const float* x   = (const float*)d_in[0];
    const float* ips = (const float*)d_in[1];
    const float* w1  = (const float*)d_in[2];
    const float* b1  = (const float*)d_in[3];
    const float* g1  = (const float*)d_in[4];
    const float* be1 = (const float*)d_in[5];
    const float* w2  = (const float*)d_in[6];
    const float* b2  = (const float*)d_in[7];
    const float* g2  = (const float*)d_in[8];
    const float* be2 = (const float*)d_in[9];
    const float* w3  = (const float*)d_in[10];
    const float* b3  = (const float*)d_in[11];
    const float* g3  = (const float*)d_in[12];
    const float* be3 = (const float*)d_in[13];
    float* out = (float*)d_out;
    float* ws  = (float*)d_ws;

    hipLaunchKernelGGL(k1_feat, dim3(1024), dim3(256), 0, stream, x, ips, w1, b1, ws);
    hipLaunchKernelGGL(k2_red1, dim3(1),    dim3(512), 0, stream, w1, b1, g1, be1, ws);
    hipLaunchKernelGGL(k3_l2,   dim3(512),  dim3(256), 0, stream, w2, b2, w3, ws);
    hipLaunchKernelGGL(k4_red2, dim3(128),  dim3(256), 0, stream, g2, be2, ws);
    hipLaunchKernelGGL(k5_l3,   dim3(256),  dim3(512), 0, stream, b3, ws);
    hipLaunchKernelGGL(k6_out,  dim3(1024), dim3(256), 0, stream, g3, be3, out, ws);
}